// Round 4
// baseline (534.587 us; speedup 1.0000x reference)
//
#include <hip/hip_runtime.h>
#include <math.h>

#define TT 84
#define BB 96
#define GB 6            // batches per group
#define NG 16           // groups (NG*GB == BB)
#define NTOK (TT*BB)
#define RW4 6           // float4s per act row: 24 floats = [fwd 10 | pad 2 | bwd 10 | pad 2]

// Gate-argument pre-scaling folded into weights/biases:
//  r,z rows scaled by -log2(e)   -> sigm(a) = rcp(1 + exp2(arg))
//  n rows scaled by -2*log2(e)   -> tanh(x) = 2*rcp(1 + exp2(arg)) - 1
#define S_RZ (-1.4426950408889634f)
#define S_N  (-2.8853900817779268f)

__device__ __forceinline__ float frcp(float x)  { return __builtin_amdgcn_rcpf(x); }
__device__ __forceinline__ float fexp2(float x) { return __builtin_amdgcn_exp2f(x); }

// DPP row_ror:M within 16-lane rows: dst lane i <- src lane (i-M) & 15
template<int M>
__device__ __forceinline__ float dpp_ror(float v) {
    return __int_as_float(__builtin_amdgcn_update_dpp(
        0, __float_as_int(v), 0x120 + M, 0xf, 0xf, true));
}

// ---------------- layer-0 projection: emb gather + E=400 dot (pre-scaled) ----
__global__ __launch_bounds__(256) void proj0_kernel(
    const int* __restrict__ x, const float* __restrict__ emb,
    const float* __restrict__ wih0, const float* __restrict__ bih0,
    float* __restrict__ xp, unsigned int* __restrict__ bar)
{
    if (blockIdx.x == 0 && threadIdx.x == 0) bar[0] = 0u;  // re-zero grid barrier
    __shared__ float4 xrow[32][100];   // 32 tokens x 400 floats
    const int tok0 = blockIdx.x * 32;
    for (int u = threadIdx.x; u < 32*100; u += 256) {
        int tk = u / 100, i4 = u % 100;
        int row = x[tok0 + tk];
        xrow[tk][i4] = ((const float4*)emb)[row*100 + i4];
    }
    __syncthreads();
    const int g64 = threadIdx.x & 63;
    const int q   = threadIdx.x >> 6;          // 0..3, 8 tokens each
    if (g64 >= 60) return;
    const int dir = g64 / 30, gg = g64 % 30;
    const float sc = (gg < 20) ? S_RZ : S_N;
    const float bias = bih0[dir*30 + gg];
    float acc[8];
    #pragma unroll
    for (int c = 0; c < 8; ++c) acc[c] = bias;
    const float4* w4 = ((const float4*)wih0) + (dir*30 + gg)*100;
    for (int i4 = 0; i4 < 100; ++i4) {
        float4 w = w4[i4];
        #pragma unroll
        for (int c = 0; c < 8; ++c) {
            float4 xv = xrow[q*8 + c][i4];
            acc[c] += w.x*xv.x + w.y*xv.y + w.z*xv.z + w.w*xv.w;
        }
    }
    #pragma unroll
    for (int c = 0; c < 8; ++c) {
        int tok = tok0 + q*8 + c;
        int t = tok / BB, b = tok % BB;
        xp[((size_t)((dir*TT + t)*BB + b))*30 + gg] = acc[c]*sc;
    }
}

// proj over 20 channels from a padded 24-float act row
__device__ __forceinline__ void proj20(
    const float4* A, const float* wpr, const float* wpz, const float* wpn,
    float bir, float biz, float bin, float& xr, float& xz, float& xn)
{
    float a[24];
    #pragma unroll
    for (int q = 0; q < 6; ++q) {
        a[4*q]=A[q].x; a[4*q+1]=A[q].y; a[4*q+2]=A[q].z; a[4*q+3]=A[q].w;
    }
    xr = bir; xz = biz; xn = bin;
    #pragma unroll
    for (int c = 0; c < 20; ++c) {
        float av = a[c + (c >= 10 ? 2 : 0)];
        xr = fmaf(wpr[c], av, xr); xz = fmaf(wpz[c], av, xz); xn = fmaf(wpn[c], av, xn);
    }
}

// ---------------- scan: one seq per 16-lane row, h all-gather via DPP ror ----
// Lane = channel j (0..9 real, 10..15 pad). Recurrence chain is pure
// VALU+DPP: no LDS on the critical path. act4 write is fire-and-forget
// (consumed by the boundary pass after the barrier); pad lanes redirect
// their act write to an LDS trash slot (cndmask, no branch). Pad lanes read
// channel-9 x (clamped, in-bounds, finite) so their hnew is always finite;
// real lanes multiply pad slots by exactly-zero weights.
template<bool LAST>
__device__ __forceinline__ void scan16(
    const float* __restrict__ xb,     // xp + dir*TT*BB*30 (lane's dir folded in)
    const float* __restrict__ wh, const float* __restrict__ bh3,
    float* __restrict__ actF, float* __restrict__ actG,
    int j, int jw, int bl, int dir, int b, int dt, int t0,
    bool realw, int trashIdx)
{
    // rotation-slot weights: wslot[m] pairs with h_rel[m] = h[(j-m)&15]
    float wsr[16], wsz[16], wsn[16];
    #pragma unroll
    for (int m = 0; m < 16; ++m) {
        int k  = (j - m) & 15;        // if absmax blows up: flip to (j + m) & 15
        int kc = (k < 10) ? k : 9;
        float zr = (k < 10) ? S_RZ : 0.f;
        float zn = (k < 10) ? S_N  : 0.f;
        wsr[m] = wh[       jw*10 + kc] * zr;
        wsz[m] = wh[100 +  jw*10 + kc] * zr;
        wsn[m] = wh[200 +  jw*10 + kc] * zn;
    }
    const float bhr = bh3[jw]*S_RZ, bhz = bh3[10+jw]*S_RZ, bhn = bh3[20+jw]*S_N;

    float h[16];
    #pragma unroll
    for (int m = 0; m < 16; ++m) h[m] = 0.f;

    int t = t0;
    const size_t lbo = (size_t)b*30 + jw;       // clamped channel for pad lanes
    float xr0 = xb[(size_t)t0*(BB*30) + lbo];
    float xz0 = xb[(size_t)t0*(BB*30) + lbo + 10];
    float xn0 = xb[(size_t)t0*(BB*30) + lbo + 20];
    const int t1 = t0 + dt;
    float xr1 = xb[(size_t)t1*(BB*30) + lbo];
    float xz1 = xb[(size_t)t1*(BB*30) + lbo + 10];
    float xn1 = xb[(size_t)t1*(BB*30) + lbo + 20];

    #pragma unroll 1
    for (int s = 0; s < TT; ++s) {
        // dots over 16 rotation slots, 2 accumulators per gate
        float ar0 = fmaf(wsr[0], h[0], xr0 + bhr), ar1 = wsr[1]*h[1];
        float az0 = fmaf(wsz[0], h[0], xz0 + bhz), az1 = wsz[1]*h[1];
        float an0 = fmaf(wsn[0], h[0], bhn),       an1 = wsn[1]*h[1];
        #pragma unroll
        for (int m = 2; m < 16; m += 2) {
            ar0 = fmaf(wsr[m], h[m], ar0); ar1 = fmaf(wsr[m+1], h[m+1], ar1);
            az0 = fmaf(wsz[m], h[m], az0); az1 = fmaf(wsz[m+1], h[m+1], az1);
            an0 = fmaf(wsn[m], h[m], an0); an1 = fmaf(wsn[m+1], h[m+1], an1);
        }
        float r  = frcp(1.f + fexp2(ar0 + ar1));
        float z  = frcp(1.f + fexp2(az0 + az1));
        float an = fmaf(r, an0 + an1, xn0);
        float n  = fmaf(2.f, frcp(1.f + fexp2(an)), -1.f);
        float hown = h[0];
        float hnew = n + z*(hown - n);

        // act write (off-chain; trash-redirect for pad lanes)
        int widx = realw ? ((t*GB + bl)*24 + dir*12 + j) : trashIdx;
        actF[widx] = hnew;
        if (LAST) {
            if (realw) actG[(size_t)(t*BB + b)*20 + dir*10 + j] = hnew;
        }

        // h all-gather: 15 DPP row rotations (VALU latency, no LDS)
        h[0]  = hnew;
        h[1]  = dpp_ror<1>(hnew);
        h[2]  = dpp_ror<2>(hnew);
        h[3]  = dpp_ror<3>(hnew);
        h[4]  = dpp_ror<4>(hnew);
        h[5]  = dpp_ror<5>(hnew);
        h[6]  = dpp_ror<6>(hnew);
        h[7]  = dpp_ror<7>(hnew);
        h[8]  = dpp_ror<8>(hnew);
        h[9]  = dpp_ror<9>(hnew);
        h[10] = dpp_ror<10>(hnew);
        h[11] = dpp_ror<11>(hnew);
        h[12] = dpp_ror<12>(hnew);
        h[13] = dpp_ror<13>(hnew);
        h[14] = dpp_ror<14>(hnew);
        h[15] = dpp_ror<15>(hnew);

        // advance x prefetch (2-deep)
        int tp = t + 2*dt; tp = tp < 0 ? 0 : (tp > TT-1 ? TT-1 : tp);
        xr0 = xr1; xz0 = xz1; xn0 = xn1;
        const float* px = xb + (size_t)tp*(BB*30) + lbo;
        xr1 = px[0]; xz1 = px[10]; xn1 = px[20];
        t += dt;
    }
}

// ---------------- mega: all 10 layers + head, 16 blocks x 256 ----------------
__global__ __launch_bounds__(256, 1) void mega_kernel(
    float* __restrict__ xp,             // read-write: layer-l inputs, overwritten per layer
    const float* __restrict__ whh0, const float* __restrict__ bhh0,
    const float* __restrict__ wih,  const float* __restrict__ bih,
    const float* __restrict__ whh,  const float* __restrict__ bhh,
    const float* __restrict__ lin_w, const float* __restrict__ lin_b,
    float* __restrict__ actG, unsigned int* __restrict__ bar,
    float* __restrict__ out)
{
    __shared__ float4 act4[TT*GB*RW4 + 16];   // 48384 B act + 256 B trash

    const int tid  = threadIdx.x;
    const int grp  = blockIdx.x;
    const int wid  = tid >> 6;
    const int lane = tid & 63;

    // scan mapping: waves 0..2, seq = wid*4 + row, one seq per 16-lane row
    const bool scanw = (wid < 3);
    const int seq  = wid*4 + (lane >> 4);      // 0..11 (valid for scan waves)
    const int rl   = lane & 15;                // channel j (0..9 real)
    const int dirS = (seq >= 6) ? 1 : 0;
    const int blS  = seq - dirS*6;
    const int jS   = rl;
    const int jwS  = (rl < 10) ? rl : 9;
    const bool realw = (rl < 10);
    const int bS   = grp*GB + blS;
    const int dtS  = dirS ? -1 : 1;
    const int t0S  = dirS ? TT-1 : 0;
    const int trashIdx = TT*GB*RW4*4 + lane;   // float index into act4 region

    // boundary-proj mapping (240 of 256 threads: 2 t-halves x 2 dir x 6 b x 10 ch)
    const int half = tid / 120;
    const int prr  = tid % 120;
    const int dp   = prr / 60;
    const int prr2 = prr % 60;
    const int blp  = prr2 / 10;
    const int jp   = prr2 % 10;

    #pragma unroll 1
    for (int l = 0; l < 9; ++l) {
        if (scanw) {
            const float* wh  = (l == 0) ? (whh0 + dirS*300)
                                        : (whh + (size_t)((l-1)*2 + dirS)*300);
            const float* bh3 = (l == 0) ? (bhh0 + dirS*30)
                                        : (bhh + (size_t)((l-1)*2 + dirS)*30);
            scan16<false>(xp + (size_t)dirS*TT*BB*30, wh, bh3,
                          (float*)act4, actG, jS, jwS, blS, dirS, bS, dtS, t0S,
                          realw, trashIdx);
        }
        __syncthreads();
        // boundary pass: xp for layer l+1 from act4, all 4 waves
        if (tid < 240) {
            const float* wi = wih + (size_t)(l*2 + dp)*600;
            const float* bi = bih + (size_t)(l*2 + dp)*30;
            float wpr[20], wpz[20], wpn[20];
            {
                const float4* p0 = (const float4*)(wi + jp*20);
                const float4* p1 = (const float4*)(wi + (10+jp)*20);
                const float4* p2 = (const float4*)(wi + (20+jp)*20);
                #pragma unroll
                for (int q = 0; q < 5; ++q) {
                    float4 a = p0[q]; wpr[4*q]=a.x*S_RZ; wpr[4*q+1]=a.y*S_RZ; wpr[4*q+2]=a.z*S_RZ; wpr[4*q+3]=a.w*S_RZ;
                    float4 c = p1[q]; wpz[4*q]=c.x*S_RZ; wpz[4*q+1]=c.y*S_RZ; wpz[4*q+2]=c.z*S_RZ; wpz[4*q+3]=c.w*S_RZ;
                    float4 d = p2[q]; wpn[4*q]=d.x*S_N;  wpn[4*q+1]=d.y*S_N;  wpn[4*q+2]=d.z*S_N;  wpn[4*q+3]=d.w*S_N;
                }
            }
            const float bir = bi[jp]*S_RZ, biz = bi[10+jp]*S_RZ, bin = bi[20+jp]*S_N;
            const int bg = grp*GB + blp;
            #pragma unroll 1
            for (int t = half*(TT/2); t < (half+1)*(TT/2); ++t) {
                float xr, xz, xn;
                proj20(&act4[(t*GB + blp)*RW4], wpr, wpz, wpn, bir, biz, bin, xr, xz, xn);
                float* px = xp + ((size_t)(dp*TT + t)*BB + bg)*30;
                px[jp] = xr; px[10+jp] = xz; px[20+jp] = xn;
            }
        }
        __syncthreads();
    }
    // layer 9: writes actG
    if (scanw) {
        const float* wh  = whh + (size_t)(8*2 + dirS)*300;
        const float* bh3 = bhh + (size_t)(8*2 + dirS)*30;
        scan16<true>(xp + (size_t)dirS*TT*BB*30, wh, bh3,
                     (float*)act4, actG, jS, jwS, blS, dirS, bS, dtS, t0S,
                     realw, trashIdx);
    }

    // ---- grid barrier (16 blocks, all co-resident) ----
    __threadfence();
    __syncthreads();
    if (tid == 0) {
        __hip_atomic_fetch_add(bar, 1u, __ATOMIC_ACQ_REL, __HIP_MEMORY_SCOPE_AGENT);
        while (__hip_atomic_load(bar, __ATOMIC_ACQUIRE, __HIP_MEMORY_SCOPE_AGENT) < (unsigned)NG)
            __builtin_amdgcn_s_sleep(1);
    }
    __syncthreads();
    __threadfence();

    // ---- head: rows r = grp*6 .. grp*6+5 (feat aliases act4) ----
    float* feat = (float*)act4;
    for (int u = tid; u < GB*336; u += 256) {
        int q = u / 336, v = u % 336;
        int r = grp*GB + q;
        int qq = v / 12, f = v % 12;
        int pair = r*28 + qq;           // t*32 + bb
        int t = pair / 32, bb = pair % 32;
        int jj = (f < 6) ? f : f - 6;
        float acc = (f < 6) ? 0.f : -1e30f;
        #pragma unroll
        for (int i = 0; i < 3; ++i) {
            #pragma unroll
            for (int kk = 0; kk < 3; ++kk) {
                float vv = actG[(size_t)(t*BB + bb*3 + i)*20 + jj*3 + kk];
                if (f < 6) acc += vv; else acc = fmaxf(acc, vv);
            }
        }
        feat[u] = (f < 6) ? acc*(1.f/9.f) : acc;
    }
    __syncthreads();
    if (tid < GB*19) {
        int q = tid / 19, o = tid % 19;
        int r = grp*GB + q;
        float acc = lin_b[o];
        const float* wrow = lin_w + o*336;
        const float* frow = feat + q*336;
        for (int v = 0; v < 336; ++v) acc = fmaf(frow[v], wrow[v], acc);
        out[r*19 + o] = frcp(1.f + __expf(-acc));
    }
}

extern "C" void kernel_launch(void* const* d_in, const int* in_sizes, int n_in,
                              void* d_out, int out_size, void* d_ws, size_t ws_size,
                              hipStream_t stream)
{
    const int*   x     = (const int*)  d_in[0];
    const float* emb   = (const float*)d_in[1];
    const float* wih0  = (const float*)d_in[2];
    const float* whh0  = (const float*)d_in[3];
    const float* bih0  = (const float*)d_in[4];
    const float* bhh0  = (const float*)d_in[5];
    const float* wih   = (const float*)d_in[6];
    const float* whh   = (const float*)d_in[7];
    const float* bih   = (const float*)d_in[8];
    const float* bhh   = (const float*)d_in[9];
    const float* lin_w = (const float*)d_in[10];
    const float* lin_b = (const float*)d_in[11];
    float* out = (float*)d_out;

    float* xp0  = (float*)d_ws;                    // 2*84*96*30 = 483840 floats
    float* actG = xp0 + (size_t)2*NTOK*30;         // 84*96*20   = 161280 floats
    unsigned int* bar = (unsigned int*)(actG + (size_t)NTOK*20);

    proj0_kernel<<<252, 256, 0, stream>>>(x, emb, wih0, bih0, xp0, bar);
    mega_kernel<<<NG, 256, 0, stream>>>(xp0, whh0, bhh0, wih, bih, whh, bhh,
                                        lin_w, lin_b, actG, bar, out);
}

// Round 7
// 438.501 us; speedup vs baseline: 1.2191x; 1.2191x over previous
//
#include <hip/hip_runtime.h>
#include <math.h>

#define TT 84
#define BB 96
#define GB 6            // batches per group
#define NG 16           // groups (NG*GB == BB)
#define NTOK (TT*BB)
#define RW4 6           // float4s per act row: 24 floats = [fwd 10 | pad 2 | bwd 10 | pad 2]

// Gate-argument pre-scaling folded into weights/biases:
//  r,z rows scaled by -log2(e)   -> sigm(a) = rcp(1 + exp2(arg))
//  n rows scaled by -2*log2(e)   -> tanh(x) = 2*rcp(1 + exp2(arg)) - 1
#define S_RZ (-1.4426950408889634f)
#define S_N  (-2.8853900817779268f)

typedef float v2f __attribute__((ext_vector_type(2)));
typedef float v4f __attribute__((ext_vector_type(4)));

__device__ __forceinline__ float frcp(float x)  { return __builtin_amdgcn_rcpf(x); }
__device__ __forceinline__ float fexp2(float x) { return __builtin_amdgcn_exp2f(x); }
__device__ __forceinline__ v2f   fma2(v2f a, v2f b, v2f c) {
    return __builtin_elementwise_fma(a, b, c);   // -> v_pk_fma_f32
}

// ---------------- layer-0 projection: emb gather + E=400 dot (pre-scaled) ----
// xp row layout (30 floats): [r0 z0 r1 z1 ... r9 z9 | n0..n9]
__global__ __launch_bounds__(256) void proj0_kernel(
    const int* __restrict__ x, const float* __restrict__ emb,
    const float* __restrict__ wih0, const float* __restrict__ bih0,
    float* __restrict__ xp, unsigned int* __restrict__ bar)
{
    if (blockIdx.x == 0 && threadIdx.x == 0) bar[0] = 0u;  // re-zero grid barrier
    __shared__ float4 xrow[32][100];   // 32 tokens x 400 floats
    const int tok0 = blockIdx.x * 32;
    for (int u = threadIdx.x; u < 32*100; u += 256) {
        int tk = u / 100, i4 = u % 100;
        int row = x[tok0 + tk];
        xrow[tk][i4] = ((const float4*)emb)[row*100 + i4];
    }
    __syncthreads();
    const int g64 = threadIdx.x & 63;
    const int q   = threadIdx.x >> 6;          // 0..3, 8 tokens each
    if (g64 >= 60) return;
    const int dir = g64 / 30, gg = g64 % 30;
    const float sc = (gg < 20) ? S_RZ : S_N;
    const float bias = bih0[dir*30 + gg];
    // interleaved output index
    const int ch  = (gg < 20) ? (gg % 10) : (gg - 20);
    const int idx = (gg < 20) ? (ch*2 + gg/10) : (20 + ch);
    float acc[8];
    #pragma unroll
    for (int c = 0; c < 8; ++c) acc[c] = bias;
    const float4* w4 = ((const float4*)wih0) + (dir*30 + gg)*100;
    for (int i4 = 0; i4 < 100; ++i4) {
        float4 w = w4[i4];
        #pragma unroll
        for (int c = 0; c < 8; ++c) {
            float4 xv = xrow[q*8 + c][i4];
            acc[c] += w.x*xv.x + w.y*xv.y + w.z*xv.z + w.w*xv.w;
        }
    }
    #pragma unroll
    for (int c = 0; c < 8; ++c) {
        int tok = tok0 + q*8 + c;
        int t = tok / BB, b = tok % BB;
        xp[((size_t)((dir*TT + t)*BB + b))*30 + idx] = acc[c]*sc;
    }
}

// proj over 20 channels from a padded 24-float act row
__device__ __forceinline__ void proj20(
    const float4* A, const float* wpr, const float* wpz, const float* wpn,
    float bir, float biz, float bin, float& xr, float& xz, float& xn)
{
    float a[24];
    #pragma unroll
    for (int q = 0; q < 6; ++q) {
        a[4*q]=A[q].x; a[4*q+1]=A[q].y; a[4*q+2]=A[q].z; a[4*q+3]=A[q].w;
    }
    xr = bir; xz = biz; xn = bin;
    #pragma unroll
    for (int c = 0; c < 20; ++c) {
        float av = a[c + (c >= 10 ? 2 : 0)];
        xr = fmaf(wpr[c], av, xr); xz = fmaf(wpz[c], av, xz); xn = fmaf(wpn[c], av, xn);
    }
}

// ---------------- lean scan: pk-fp32 dots, LDS h-exchange, unroll-2 ----------
template<bool LAST>
__device__ __forceinline__ void scan_layer(
    const float* __restrict__ xb,       // xp + dir plane, layout [t][BB][30] interleaved
    const float* __restrict__ wh, const float* __restrict__ bh3,
    float* __restrict__ actF, float* __restrict__ actG,
    int bl, int j, bool act_ln, int b, int dir, int dt, int t0)
{
    // weight pairs: wr2[q] pairs with h pair {h2q, h2q+1}
    v2f wr2[5], wz2[5], wn2[5];
    {
        const v2f* p0 = (const v2f*)(wh + j*10);
        const v2f* p1 = (const v2f*)(wh + (10+j)*10);
        const v2f* p2 = (const v2f*)(wh + (20+j)*10);
        #pragma unroll
        for (int q = 0; q < 5; ++q) {
            wr2[q] = p0[q] * S_RZ;
            wz2[q] = p1[q] * S_RZ;
            wn2[q] = p2[q] * S_N;
        }
    }
    const v2f br2 = {bh3[j]*S_RZ,    0.f};
    const v2f bz2 = {bh3[10+j]*S_RZ, 0.f};
    const v2f bn2 = {bh3[20+j]*S_N,  0.f};

    v2f H0 = {0,0}, H1 = {0,0}, H2 = {0,0}, H3 = {0,0}, H4 = {0,0};
    float hown = 0.f;
    int t = t0;

    // 2-deep x prefetch, double-buffered (no shift moves)
    const int xoff = 2*j, noff = 20 + j;
    v2f  rzA = *(const v2f*)(xb + (size_t)(t0*BB + b)*30 + xoff);
    float xnA = xb[(size_t)(t0*BB + b)*30 + noff];
    v2f  rzB = *(const v2f*)(xb + (size_t)((t0+dt)*BB + b)*30 + xoff);
    float xnB = xb[(size_t)((t0+dt)*BB + b)*30 + noff];

    const float* arow = actF;   // act base (float view)

    #define GRU_STEP(RZ, XN)                                                  \
    {                                                                         \
        v2f ar = fma2(wr2[0], H0, br2);                                       \
        v2f az = fma2(wz2[0], H0, bz2);                                       \
        v2f an2 = fma2(wn2[0], H0, bn2);                                      \
        ar = fma2(wr2[1], H1, ar); az = fma2(wz2[1], H1, az); an2 = fma2(wn2[1], H1, an2); \
        ar = fma2(wr2[2], H2, ar); az = fma2(wz2[2], H2, az); an2 = fma2(wn2[2], H2, an2); \
        ar = fma2(wr2[3], H3, ar); az = fma2(wz2[3], H3, az); an2 = fma2(wn2[3], H3, an2); \
        ar = fma2(wr2[4], H4, ar); az = fma2(wz2[4], H4, az); an2 = fma2(wn2[4], H4, an2); \
        float r  = frcp(1.f + fexp2((RZ.x + ar.x) + ar.y));                   \
        float z  = frcp(1.f + fexp2((RZ.y + az.x) + az.y));                   \
        float an = fmaf(r, an2.x + an2.y, XN);                                \
        float n  = fmaf(2.f, frcp(1.f + fexp2(an)), -1.f);                    \
        float hnew = n + z*(hown - n);                                        \
        hown = hnew;                                                          \
        int rowf = (t*GB + bl)*24 + dir*12;                                   \
        ((float*)arow)[rowf + j] = hnew;                /* ds_write */        \
        const v4f* hr = (const v4f*)(arow + rowf);                            \
        v4f ha = hr[0], hb = hr[1];                      /* 2x ds_read_b128 */\
        v2f hc = *(const v2f*)(arow + rowf + 8);         /* ds_read_b64 */    \
        H0 = ha.xy; H1 = ha.zw; H2 = hb.xy; H3 = hb.zw; H4 = hc;              \
        __builtin_amdgcn_sched_barrier(0);                                    \
        if (LAST) { if (act_ln) actG[(size_t)(t*BB + b)*20 + dir*10 + j] = hnew; } \
    }

    #pragma unroll 1
    for (int s = 0; s < TT; s += 2) {
        // half A
        GRU_STEP(rzA, xnA)
        {
            int tp = t + 2*dt; tp = tp < 0 ? 0 : (tp > TT-1 ? TT-1 : tp);
            const float* px = xb + (size_t)(tp*BB + b)*30;
            rzA = *(const v2f*)(px + xoff); xnA = px[noff];
            t += dt;
        }
        // half B
        GRU_STEP(rzB, xnB)
        {
            int tp = t + 2*dt; tp = tp < 0 ? 0 : (tp > TT-1 ? TT-1 : tp);
            const float* px = xb + (size_t)(tp*BB + b)*30;
            rzB = *(const v2f*)(px + xoff); xnB = px[noff];
            t += dt;
        }
    }
    #undef GRU_STEP
}

// ---------------- mega: all 10 layers + head, 16 blocks x 256 ----------------
__global__ __launch_bounds__(256, 1) void mega_kernel(
    float* __restrict__ xp,             // read-write: layer-l inputs, overwritten per layer
    const float* __restrict__ whh0, const float* __restrict__ bhh0,
    const float* __restrict__ wih,  const float* __restrict__ bih,
    const float* __restrict__ whh,  const float* __restrict__ bhh,
    const float* __restrict__ lin_w, const float* __restrict__ lin_b,
    float* __restrict__ actG, unsigned int* __restrict__ bar,
    float* __restrict__ out)
{
    __shared__ float4 act4[TT*GB*RW4];    // 48384 B, single buffer

    const int tid  = threadIdx.x;
    const int grp  = blockIdx.x;

    // scan mapping (waves 0,1)
    const int dir  = (tid >> 6) & 1;
    const int lane = tid & 63;
    int bl = lane / 10; if (bl > 5) bl = 5;
    int j  = lane - bl*10; if (j > 9) j = 9;
    const bool act_ln = (lane < 60);
    const int b  = grp*GB + bl;
    const int dt = dir ? -1 : 1;
    const int t0 = dir ? TT-1 : 0;

    // boundary-proj mapping (240 of 256 threads: 2 t-halves x 2 dir x 6 b x 10 ch)
    const int half = tid / 120;
    const int prr  = tid % 120;
    const int dp   = prr / 60;
    const int prr2 = prr % 60;
    const int blp  = prr2 / 10;
    const int jp   = prr2 % 10;

    #pragma unroll 1
    for (int l = 0; l < 9; ++l) {
        if (tid < 128) {
            const float* wh  = (l == 0) ? (whh0 + dir*300)
                                        : (whh + (size_t)((l-1)*2 + dir)*300);
            const float* bh3 = (l == 0) ? (bhh0 + dir*30)
                                        : (bhh + (size_t)((l-1)*2 + dir)*30);
            scan_layer<false>(xp + (size_t)dir*TT*BB*30, wh, bh3,
                              (float*)act4, actG, bl, j, act_ln, b, dir, dt, t0);
        }
        __syncthreads();
        // boundary pass: xp for layer l+1 from act4, all 4 waves
        if (tid < 240) {
            const float* wi = wih + (size_t)(l*2 + dp)*600;
            const float* bi = bih + (size_t)(l*2 + dp)*30;
            float wpr[20], wpz[20], wpn[20];
            {
                const float4* p0 = (const float4*)(wi + jp*20);
                const float4* p1 = (const float4*)(wi + (10+jp)*20);
                const float4* p2 = (const float4*)(wi + (20+jp)*20);
                #pragma unroll
                for (int q = 0; q < 5; ++q) {
                    float4 a = p0[q]; wpr[4*q]=a.x*S_RZ; wpr[4*q+1]=a.y*S_RZ; wpr[4*q+2]=a.z*S_RZ; wpr[4*q+3]=a.w*S_RZ;
                    float4 c = p1[q]; wpz[4*q]=c.x*S_RZ; wpz[4*q+1]=c.y*S_RZ; wpz[4*q+2]=c.z*S_RZ; wpz[4*q+3]=c.w*S_RZ;
                    float4 d = p2[q]; wpn[4*q]=d.x*S_N;  wpn[4*q+1]=d.y*S_N;  wpn[4*q+2]=d.z*S_N;  wpn[4*q+3]=d.w*S_N;
                }
            }
            const float bir = bi[jp]*S_RZ, biz = bi[10+jp]*S_RZ, bin = bi[20+jp]*S_N;
            const int bg = grp*GB + blp;
            #pragma unroll 1
            for (int t = half*(TT/2); t < (half+1)*(TT/2); ++t) {
                float xr, xz, xn;
                proj20(&act4[(t*GB + blp)*RW4], wpr, wpz, wpn, bir, biz, bin, xr, xz, xn);
                float* px = xp + ((size_t)(dp*TT + t)*BB + bg)*30;
                *(v2f*)(px + 2*jp) = (v2f){xr, xz};
                px[20+jp] = xn;
            }
        }
        __syncthreads();
    }
    // layer 9: writes actG
    if (tid < 128) {
        const float* wh  = whh + (size_t)(8*2 + dir)*300;
        const float* bh3 = bhh + (size_t)(8*2 + dir)*30;
        scan_layer<true>(xp + (size_t)dir*TT*BB*30, wh, bh3,
                         (float*)act4, actG, bl, j, act_ln, b, dir, dt, t0);
    }

    // ---- grid barrier (16 blocks, all co-resident) ----
    __threadfence();
    __syncthreads();
    if (tid == 0) {
        __hip_atomic_fetch_add(bar, 1u, __ATOMIC_ACQ_REL, __HIP_MEMORY_SCOPE_AGENT);
        while (__hip_atomic_load(bar, __ATOMIC_ACQUIRE, __HIP_MEMORY_SCOPE_AGENT) < (unsigned)NG)
            __builtin_amdgcn_s_sleep(1);
    }
    __syncthreads();
    __threadfence();

    // ---- head: rows r = grp*6 .. grp*6+5 (feat aliases act4) ----
    float* feat = (float*)act4;
    for (int u = tid; u < GB*336; u += 256) {
        int q = u / 336, v = u % 336;
        int r = grp*GB + q;
        int qq = v / 12, f = v % 12;
        int pair = r*28 + qq;           // t*32 + bb
        int t = pair / 32, bb = pair % 32;
        int jj = (f < 6) ? f : f - 6;
        float acc = (f < 6) ? 0.f : -1e30f;
        #pragma unroll
        for (int i = 0; i < 3; ++i) {
            #pragma unroll
            for (int kk = 0; kk < 3; ++kk) {
                float vv = actG[(size_t)(t*BB + bb*3 + i)*20 + jj*3 + kk];
                if (f < 6) acc += vv; else acc = fmaxf(acc, vv);
            }
        }
        feat[u] = (f < 6) ? acc*(1.f/9.f) : acc;
    }
    __syncthreads();
    if (tid < GB*19) {
        int q = tid / 19, o = tid % 19;
        int r = grp*GB + q;
        float acc = lin_b[o];
        const float* wrow = lin_w + o*336;
        const float* frow = feat + q*336;
        for (int v = 0; v < 336; ++v) acc = fmaf(frow[v], wrow[v], acc);
        out[r*19 + o] = frcp(1.f + __expf(-acc));
    }
}

extern "C" void kernel_launch(void* const* d_in, const int* in_sizes, int n_in,
                              void* d_out, int out_size, void* d_ws, size_t ws_size,
                              hipStream_t stream)
{
    const int*   x     = (const int*)  d_in[0];
    const float* emb   = (const float*)d_in[1];
    const float* wih0  = (const float*)d_in[2];
    const float* whh0  = (const float*)d_in[3];
    const float* bih0  = (const float*)d_in[4];
    const float* bhh0  = (const float*)d_in[5];
    const float* wih   = (const float*)d_in[6];
    const float* whh   = (const float*)d_in[7];
    const float* bih   = (const float*)d_in[8];
    const float* bhh   = (const float*)d_in[9];
    const float* lin_w = (const float*)d_in[10];
    const float* lin_b = (const float*)d_in[11];
    float* out = (float*)d_out;

    float* xp0  = (float*)d_ws;                    // 2*84*96*30 = 483840 floats
    float* actG = xp0 + (size_t)2*NTOK*30;         // 84*96*20   = 161280 floats
    unsigned int* bar = (unsigned int*)(actG + (size_t)NTOK*20);

    proj0_kernel<<<252, 256, 0, stream>>>(x, emb, wih0, bih0, xp0, bar);
    mega_kernel<<<NG, 256, 0, stream>>>(xp0, whh0, bhh0, wih, bih, whh, bhh,
                                        lin_w, lin_b, actG, bar, out);
}